// Round 3
// baseline (6771.091 us; speedup 1.0000x reference)
//
#include <hip/hip_runtime.h>
#include <hip/hip_bf16.h>
#include <math.h>

// Problem constants
#define H 450
#define LAT 56
#define V 780
#define LW 24
#define NF 23
#define NE 46

#define STEPF (1024*450)             // 460,800
#define SROWS 2048                   // two chains batched
#define QROWS (24*1024)              // 24576
#define PSCAN (46*1024)              // 47104
#define PROWS (47*1024)              // 48128
#define PTGT  (23*1024)              // 23552

typedef __hip_bfloat16 bf16;

__device__ __forceinline__ float sigm(float x) { return 1.f / (1.f + expf(-x)); }
__device__ __forceinline__ float toF(float x) { return x; }
__device__ __forceinline__ float toF(bf16 x) { return __bfloat162float(x); }
__device__ __forceinline__ void stV(float* p, float v) { *p = v; }
__device__ __forceinline__ void stV(bf16* p, float v) { *p = __float2bfloat16(v); }

// zero out[4], Sb0, RM (n = SROWS*H each)
__global__ __launch_bounds__(256)
void zero_init(float* __restrict__ out, float* __restrict__ Sb0,
               float* __restrict__ RM, int n) {
    int i = blockIdx.x * 256 + threadIdx.x;
    if (i < 4) out[i] = 0.f;
    if (i < n) { Sb0[i] = 0.f; RM[i] = 0.f; }
}

// x_all[t][n][h] = emb[wid[n][t]][h]  (bf16 out)
__global__ __launch_bounds__(256)
void gather_x(const float* __restrict__ emb, const int* __restrict__ wid,
              bf16* __restrict__ x_all) {
    int e = blockIdx.x * 256 + threadIdx.x;                 // over 24*1024*225
    if (e >= 24 * 1024 * 225) return;
    int row = e / 225;
    int h2  = e - row * 225;
    int t = row >> 10, n = row & 1023;
    int v = wid[n * LW + t];
    const float2* src = (const float2*)(emb + (size_t)v * H);
    float2 x = src[h2];
    bf16* dst = x_all + (size_t)row * H + 2 * h2;
    dst[0] = __float2bfloat16(x.x);
    dst[1] = __float2bfloat16(x.y);
}

// ---------------------------------------------------------------------------
// Generic GEMM: C[MxN] = act(A[MxK] @ B[KxN] + bias[col] + addrow[(r%mod)*N+c])
// A: fp32 or bf16; B: fp32; C: fp32 or bf16. 64x64 tile, 256 thr, 4x4 micro.
// ---------------------------------------------------------------------------
template<typename TA, typename TC>
__global__ __launch_bounds__(256)
void gemm_t(const TA* __restrict__ A, int M, int lda,
            const float* __restrict__ B, int N, int ldb,
            TC* __restrict__ C, int ldc,
            const float* __restrict__ bias,
            const float* __restrict__ addrow, int addmod,
            int relu_flag, int K) {
    __shared__ float As[16][64];
    __shared__ float Bs[16][64];
    int tid = threadIdx.x;
    int tx = tid & 15, ty = tid >> 4;
    int row0 = blockIdx.y * 64, col0 = blockIdx.x * 64;
    float acc[4][4] = {};
    int am = tid >> 2, ak = (tid & 3) * 4;
    int bn = tid & 63, bk = tid >> 6;
    for (int k0 = 0; k0 < K; k0 += 16) {
        bool mok = (row0 + am) < M;
        const TA* Ap = A + (size_t)(row0 + am) * lda + k0 + ak;
#pragma unroll
        for (int i = 0; i < 4; i++) {
            int kk = k0 + ak + i;
            As[ak + i][am] = (mok && kk < K) ? toF(Ap[i]) : 0.f;
        }
#pragma unroll
        for (int i = 0; i < 4; i++) {
            int kk = k0 + bk + i * 4;
            bool ok = (kk < K) && (col0 + bn < N);
            Bs[bk + i * 4][bn] = ok ? B[(size_t)kk * ldb + col0 + bn] : 0.f;
        }
        __syncthreads();
#pragma unroll
        for (int kk = 0; kk < 16; kk++) {
            float a[4], b[4];
#pragma unroll
            for (int i = 0; i < 4; i++) a[i] = As[kk][ty * 4 + i];
#pragma unroll
            for (int j = 0; j < 4; j++) b[j] = Bs[kk][tx * 4 + j];
#pragma unroll
            for (int i = 0; i < 4; i++)
#pragma unroll
                for (int j = 0; j < 4; j++) acc[i][j] += a[i] * b[j];
        }
        __syncthreads();
    }
#pragma unroll
    for (int i = 0; i < 4; i++) {
        int r = row0 + ty * 4 + i;
        if (r >= M) continue;
#pragma unroll
        for (int j = 0; j < 4; j++) {
            int c = col0 + tx * 4 + j;
            if (c >= N) continue;
            float v = acc[i][j];
            if (bias) v += bias[c];
            if (addrow) v += addrow[(size_t)(r % addmod) * N + c];
            if (relu_flag) v = fmaxf(v, 0.f);
            stV(&C[(size_t)r * ldc + c], v);
        }
    }
}

// Qtv/Ptv: out[n][c] = tv[n](56) @ Wlat(56x450) + bias[c]   grid(2,1024)
__global__ __launch_bounds__(256)
void tv_gemm(const float* __restrict__ tv, const float* __restrict__ Wlat,
             const float* __restrict__ bias, float* __restrict__ out) {
    int n = blockIdx.y;
    int c = blockIdx.x * 256 + threadIdx.x;
    __shared__ float tvs[LAT];
    if (threadIdx.x < LAT) tvs[threadIdx.x] = tv[n * LAT + threadIdx.x];
    __syncthreads();
    if (c < H) {
        float a = bias[c];
#pragma unroll 8
        for (int k = 0; k < LAT; k++) a += tvs[k] * Wlat[(size_t)k * H + c];
        out[(size_t)n * H + c] = a;
    }
}

// ---------------------------------------------------------------------------
// Scan K1: z_pre = Sprev@Wzb, h_pre = RMprev@Whb  (M=2048,N=450,K=450)
// epilogue: z=sig(z_pre+Xz[src]), mt=tanh(h_pre+Xh[src]), mn=(1-z)s+z*mt
// rows 0..1023 fwd (src=u,hidx=u); 1024..2047 bwd (src=23-u,hidx=23+u)
// ---------------------------------------------------------------------------
__global__ __launch_bounds__(256)
void scan_k1(const float* __restrict__ Sprev, const float* __restrict__ RMprev,
             const float* __restrict__ Wzb, const float* __restrict__ Whb,
             const bf16* __restrict__ Xz, const bf16* __restrict__ Xh,
             float* __restrict__ Mnew, bf16* __restrict__ hs, int u) {
    __shared__ float As[16][64], Ar[16][64], Bz[16][64], Bh[16][64];
    int tid = threadIdx.x;
    int tx = tid & 15, ty = tid >> 4;
    int row0 = blockIdx.y * 64, col0 = blockIdx.x * 64;
    float accz[4][4] = {}, acch[4][4] = {};
    int am = tid >> 2, ak = (tid & 3) * 4;
    int bn = tid & 63, bk = tid >> 6;
    for (int k0 = 0; k0 < H; k0 += 16) {
        const float* Sp = Sprev  + (size_t)(row0 + am) * H + k0 + ak;
        const float* Rp = RMprev + (size_t)(row0 + am) * H + k0 + ak;
#pragma unroll
        for (int i = 0; i < 4; i++) {
            int kk = k0 + ak + i;
            bool ok = kk < H;
            As[ak + i][am] = ok ? Sp[i] : 0.f;
            Ar[ak + i][am] = ok ? Rp[i] : 0.f;
        }
#pragma unroll
        for (int i = 0; i < 4; i++) {
            int kk = k0 + bk + i * 4;
            bool ok = (kk < H) && (col0 + bn < H);
            Bz[bk + i * 4][bn] = ok ? Wzb[(size_t)kk * H + col0 + bn] : 0.f;
            Bh[bk + i * 4][bn] = ok ? Whb[(size_t)kk * H + col0 + bn] : 0.f;
        }
        __syncthreads();
#pragma unroll
        for (int kk = 0; kk < 16; kk++) {
            float a0[4], a1[4], b0[4], b1[4];
#pragma unroll
            for (int i = 0; i < 4; i++) { a0[i] = As[kk][ty*4+i]; a1[i] = Ar[kk][ty*4+i]; }
#pragma unroll
            for (int j = 0; j < 4; j++) { b0[j] = Bz[kk][tx*4+j]; b1[j] = Bh[kk][tx*4+j]; }
#pragma unroll
            for (int i = 0; i < 4; i++)
#pragma unroll
                for (int j = 0; j < 4; j++) {
                    accz[i][j] += a0[i] * b0[j];
                    acch[i][j] += a1[i] * b1[j];
                }
        }
        __syncthreads();
    }
#pragma unroll
    for (int i = 0; i < 4; i++) {
        int r = row0 + ty * 4 + i;          // < 2048
        int n = r & 1023;
        bool fwd = r < 1024;
        int src  = fwd ? u : 23 - u;
        int hidx = fwd ? u : 23 + u;
        const bf16* xz = Xz + ((size_t)src * 1024 + n) * H;
        const bf16* xh = Xh + ((size_t)src * 1024 + n) * H;
#pragma unroll
        for (int j = 0; j < 4; j++) {
            int c = col0 + tx * 4 + j;
            if (c >= H) continue;
            float zp = accz[i][j] + toF(xz[c]);
            float hp = acch[i][j] + toF(xh[c]);
            float s  = Sprev[(size_t)r * H + c];
            float z  = sigm(zp);
            float mt = tanhf(hp);
            float mn = (1.f - z) * s + z * mt;
            Mnew[(size_t)r * H + c] = mn;
            stV(&hs[((size_t)hidx * 1024 + n) * H + c], mn);
        }
    }
}

// Scan K2: r_pre = Mnew@Ur + Xr[dst]; RM = sigmoid(r_pre)*Mnew
__global__ __launch_bounds__(256)
void scan_k2(const float* __restrict__ Mnew, const float* __restrict__ Ur,
             const bf16* __restrict__ Xr, float* __restrict__ RM, int u) {
    __shared__ float As[16][64], Bs[16][64];
    int tid = threadIdx.x;
    int tx = tid & 15, ty = tid >> 4;
    int row0 = blockIdx.y * 64, col0 = blockIdx.x * 64;
    float acc[4][4] = {};
    int am = tid >> 2, ak = (tid & 3) * 4;
    int bn = tid & 63, bk = tid >> 6;
    for (int k0 = 0; k0 < H; k0 += 16) {
        const float* Ap = Mnew + (size_t)(row0 + am) * H + k0 + ak;
#pragma unroll
        for (int i = 0; i < 4; i++) {
            int kk = k0 + ak + i;
            As[ak + i][am] = (kk < H) ? Ap[i] : 0.f;
        }
#pragma unroll
        for (int i = 0; i < 4; i++) {
            int kk = k0 + bk + i * 4;
            bool ok = (kk < H) && (col0 + bn < H);
            Bs[bk + i * 4][bn] = ok ? Ur[(size_t)kk * H + col0 + bn] : 0.f;
        }
        __syncthreads();
#pragma unroll
        for (int kk = 0; kk < 16; kk++) {
            float a[4], b[4];
#pragma unroll
            for (int i = 0; i < 4; i++) a[i] = As[kk][ty*4+i];
#pragma unroll
            for (int j = 0; j < 4; j++) b[j] = Bs[kk][tx*4+j];
#pragma unroll
            for (int i = 0; i < 4; i++)
#pragma unroll
                for (int j = 0; j < 4; j++) acc[i][j] += a[i] * b[j];
        }
        __syncthreads();
    }
#pragma unroll
    for (int i = 0; i < 4; i++) {
        int r = row0 + ty * 4 + i;
        int n = r & 1023;
        bool fwd = r < 1024;
        int dst = fwd ? (u + 1) : (22 - u);
        const bf16* xr = Xr + ((size_t)dst * 1024 + n) * H;
#pragma unroll
        for (int j = 0; j < 4; j++) {
            int c = col0 + tx * 4 + j;
            if (c >= H) continue;
            float rp = acc[i][j] + toF(xr[c]);
            float rr = sigm(rp);
            RM[(size_t)r * H + c] = rr * Mnew[(size_t)r * H + c];
        }
    }
}

// hs[t] += hs[44-t]  for t in 23..44
__global__ __launch_bounds__(256)
void hv_fixup(bf16* __restrict__ hs) {
    int idx = blockIdx.x * 256 + threadIdx.x;
    if (idx >= 22 * STEPF) return;
    int tl = idx / STEPF;
    int rem = idx - tl * STEPF;
    int t = 23 + tl;
    float v = toF(hs[(size_t)t * STEPF + rem]) + toF(hs[(size_t)(44 - t) * STEPF + rem]);
    stV(&hs[(size_t)t * STEPF + rem], v);
}

// q_hidden root block: relu(Qtv)
__global__ __launch_bounds__(256)
void q_root(const float* __restrict__ Qtv, bf16* __restrict__ qh) {
    int idx = blockIdx.x * 256 + threadIdx.x;
    if (idx < STEPF) stV(&qh[idx], fmaxf(Qtv[idx], 0.f));
}

// Per-row log-softmax CE + argmax accuracy over V=780. One block per row.
__global__ __launch_bounds__(256)
void q_reduce(const float* __restrict__ ql, const int* __restrict__ wid,
              float* __restrict__ out) {
    __shared__ float sv[256];
    __shared__ int   si[256];
    __shared__ float ss[256];
    int r = blockIdx.x;                    // 0..24575
    int t = r >> 10, n = r & 1023;
    int tgt = wid[n * LW + t];
    const float* row = ql + (size_t)r * V;
    int tid = threadIdx.x;
    float mx = -3.4e38f; int mi = V;
    for (int c = tid; c < V; c += 256) {
        float v = row[c];
        if (v > mx) { mx = v; mi = c; }
    }
    sv[tid] = mx; si[tid] = mi;
    __syncthreads();
    for (int s = 128; s > 0; s >>= 1) {
        if (tid < s) {
            float v2 = sv[tid + s]; int i2 = si[tid + s];
            if (v2 > sv[tid] || (v2 == sv[tid] && i2 < si[tid])) { sv[tid] = v2; si[tid] = i2; }
        }
        __syncthreads();
    }
    float MX = sv[0]; int AI = si[0];
    float se = 0.f;
    for (int c = tid; c < V; c += 256) se += expf(row[c] - MX);
    ss[tid] = se;
    __syncthreads();
    for (int s = 128; s > 0; s >>= 1) {
        if (tid < s) ss[tid] += ss[tid + s];
        __syncthreads();
    }
    if (tid == 0) {
        float lse = MX + logf(ss[0]);
        atomicAdd(&out[0], (lse - row[tgt]) * (1.f / 1024.f));
        if (AI == tgt) atomicAdd(&out[2], 1.f / 24576.f);
    }
}

__global__ __launch_bounds__(256)
void p_init(float* __restrict__ pl, const float* __restrict__ Us_b) {
    int idx = blockIdx.x * 256 + threadIdx.x;
    if (idx < PROWS) pl[idx] = Us_b[0];
}

__global__ __launch_bounds__(256)
void p_root(const bf16* __restrict__ XUa, const float* __restrict__ Ptv,
            const float* __restrict__ Us, float* __restrict__ pl) {
    int n = blockIdx.x;
    int tid = threadIdx.x;
    const bf16* xa = XUa + (size_t)n * H;
    const float* pt = Ptv + (size_t)n * H;
    float s = 0.f;
    for (int c = tid; c < H; c += 256)
        s += fmaxf(toF(xa[c]) + pt[c], 0.f) * Us[c];
    __shared__ float red[256];
    red[tid] = s;
    __syncthreads();
    for (int k = 128; k > 0; k >>= 1) {
        if (tid < k) red[tid] += red[tid + k];
        __syncthreads();
    }
    if (tid == 0) atomicAdd(&pl[n], red[0]);
}

// p scan rows: GEMM hs(47104x450)@Ub(450x450); epilogue relu(+XUa[dst]+Ptv) dot Us
__global__ __launch_bounds__(256)
void p_gemm(const bf16* __restrict__ hs, const float* __restrict__ Ub,
            const bf16* __restrict__ XUa, const float* __restrict__ Ptv,
            const float* __restrict__ Us, float* __restrict__ pl) {
    __shared__ float As[16][64], Bs[16][64];
    __shared__ float red[64][16];
    int tid = threadIdx.x;
    int tx = tid & 15, ty = tid >> 4;
    int row0 = blockIdx.y * 64, col0 = blockIdx.x * 64;
    float acc[4][4] = {};
    int am = tid >> 2, ak = (tid & 3) * 4;
    int bn = tid & 63, bk = tid >> 6;
    for (int k0 = 0; k0 < H; k0 += 16) {
        const bf16* Ap = hs + (size_t)(row0 + am) * H + k0 + ak;
#pragma unroll
        for (int i = 0; i < 4; i++) {
            int kk = k0 + ak + i;
            As[ak + i][am] = (kk < H) ? toF(Ap[i]) : 0.f;
        }
#pragma unroll
        for (int i = 0; i < 4; i++) {
            int kk = k0 + bk + i * 4;
            bool ok = (kk < H) && (col0 + bn < H);
            Bs[bk + i * 4][bn] = ok ? Ub[(size_t)kk * H + col0 + bn] : 0.f;
        }
        __syncthreads();
#pragma unroll
        for (int kk = 0; kk < 16; kk++) {
            float a[4], b[4];
#pragma unroll
            for (int i = 0; i < 4; i++) a[i] = As[kk][ty*4+i];
#pragma unroll
            for (int j = 0; j < 4; j++) b[j] = Bs[kk][tx*4+j];
#pragma unroll
            for (int i = 0; i < 4; i++)
#pragma unroll
                for (int j = 0; j < 4; j++) acc[i][j] += a[i] * b[j];
        }
        __syncthreads();
    }
#pragma unroll
    for (int i = 0; i < 4; i++) {
        int r = row0 + ty * 4 + i;
        int t = r >> 10, n = r & 1023;
        int dst = (t < 23) ? (t + 1) : (45 - t);
        const bf16* xa = XUa + ((size_t)dst * 1024 + n) * H;
        const float* pt = Ptv + (size_t)n * H;
        float partial = 0.f;
#pragma unroll
        for (int j = 0; j < 4; j++) {
            int c = col0 + tx * 4 + j;
            if (c < H) {
                float h = fmaxf(acc[i][j] + toF(xa[c]) + pt[c], 0.f);
                partial += h * Us[c];
            }
        }
        red[ty * 4 + i][tx] = partial;
    }
    __syncthreads();
    if (tid < 64) {
        float s = 0.f;
#pragma unroll
        for (int k = 0; k < 16; k++) s += red[tid][k];
        atomicAdd(&pl[1024 + row0 + tid], s);
    }
}

// BCE loss + accuracy over 48128 rows; target = (r < 23552)
__global__ __launch_bounds__(256)
void p_final(const float* __restrict__ pl, float* __restrict__ out) {
    int r = blockIdx.x * 256 + threadIdx.x;
    int tid = threadIdx.x;
    float loss = 0.f, acc = 0.f;
    if (r < PROWS) {
        float l = pl[r];
        int tgt = (r < PTGT) ? 1 : 0;
        float x = tgt ? -l : l;
        loss = fmaxf(x, 0.f) + log1pf(expf(-fabsf(x)));
        int pred = (l > 0.f) ? 1 : 0;
        acc = (pred == tgt) ? 1.f : 0.f;
    }
    __shared__ float s1[256], s2[256];
    s1[tid] = loss; s2[tid] = acc;
    __syncthreads();
    for (int k = 128; k > 0; k >>= 1) {
        if (tid < k) { s1[tid] += s1[tid + k]; s2[tid] += s2[tid + k]; }
        __syncthreads();
    }
    if (tid == 0) {
        atomicAdd(&out[1], s1[0] * (1.f / 1024.f));
        atomicAdd(&out[3], s2[0] * (1.f / 48128.f));
    }
}

// ---------------------------------------------------------------------------
extern "C" void kernel_launch(void* const* d_in, const int* in_sizes, int n_in,
                              void* d_out, int out_size, void* d_ws, size_t ws_size,
                              hipStream_t stream) {
    const int*   wid  = (const int*)  d_in[0];
    const float* tv   = (const float*)d_in[1];
    const float* emb  = (const float*)d_in[2];
    const float* W_w  = (const float*)d_in[3];
    const float* W_b  = (const float*)d_in[4];
    const float* U_w  = (const float*)d_in[5];
    const float* U_b  = (const float*)d_in[6];
    const float* Wo_w = (const float*)d_in[7];
    const float* Wo_b = (const float*)d_in[8];
    const float* Us_w = (const float*)d_in[9];
    const float* Us_b = (const float*)d_in[10];
    const float* Wz_w = (const float*)d_in[11];
    const float* Wz_b = (const float*)d_in[12];
    const float* Wr_w = (const float*)d_in[13];
    const float* Ur_w = (const float*)d_in[14];
    const float* Ur_b = (const float*)d_in[15];
    const float* Wh_w = (const float*)d_in[16];
    const float* Wh_b = (const float*)d_in[17];
    float* out = (float*)d_out;

    // weight sub-blocks (row-major (K,N) slices)
    const float* Wz_bot = Wz_w + 450 * 450;
    const float* Wh_bot = Wh_w + 450 * 450;
    const float* Ua     = U_w;
    const float* Ub     = U_w + 450 * 450;
    const float* Ulat   = U_w + 900 * 450;
    const float* Wtop   = W_w;
    const float* Wlat   = W_w + 450 * 450;

    // workspace layout (~168 MB total)
    const size_t XB = (size_t)24 * 1024 * 450;      // node-block elements
    bf16*  Xz    = (bf16*)d_ws;
    bf16*  Xh    = Xz + XB;
    bf16*  Xr    = Xh + XB;
    bf16*  XUa   = Xr + XB;
    bf16*  hs    = XUa + XB;                        // 46*STEPF bf16
    bf16*  x_all = hs;                              // alias (dead before scan)
    float* Sb0   = (float*)(hs + (size_t)NE * STEPF);
    float* Sb1   = Sb0 + (size_t)SROWS * H;
    float* RM    = Sb1 + (size_t)SROWS * H;
    float* Qtv   = RM  + (size_t)SROWS * H;
    float* Ptv   = Qtv + (size_t)STEPF;
    float* pl    = Ptv + (size_t)STEPF;             // PROWS
    bf16*  qh    = (bf16*)(pl + PROWS);             // 24576*450 bf16
    float* ql    = (float*)d_ws;                    // alias X blocks (post-p-path)

    // init
    zero_init<<<(SROWS * H + 255) / 256, 256, 0, stream>>>(out, Sb0, RM, SROWS * H);

    // embedding gather (bf16)
    gather_x<<<(24 * 1024 * 225 + 255) / 256, 256, 0, stream>>>(emb, wid, x_all);

    // per-node precomputes: 24576 x 450 @ 450 x 450  -> bf16 addend blocks
    dim3 gPre(8, QROWS / 64);
    gemm_t<bf16, bf16><<<gPre, 256, 0, stream>>>(x_all, QROWS, H, Wz_w, H, H, Xz,  H, Wz_b, (const float*)nullptr, 1, 0, H);
    gemm_t<bf16, bf16><<<gPre, 256, 0, stream>>>(x_all, QROWS, H, Wh_w, H, H, Xh,  H, Wh_b, (const float*)nullptr, 1, 0, H);
    gemm_t<bf16, bf16><<<gPre, 256, 0, stream>>>(x_all, QROWS, H, Wr_w, H, H, Xr,  H, Ur_b, (const float*)nullptr, 1, 0, H);
    gemm_t<bf16, bf16><<<gPre, 256, 0, stream>>>(x_all, QROWS, H, Ua,   H, H, XUa, H, (const float*)nullptr, (const float*)nullptr, 1, 0, H);

    // tree_vec folds
    tv_gemm<<<dim3(2, 1024), 256, 0, stream>>>(tv, Wlat, W_b, Qtv);
    tv_gemm<<<dim3(2, 1024), 256, 0, stream>>>(tv, Ulat, U_b, Ptv);

    // sequential scan: 23 combined steps (fwd + bwd chain batched)
    dim3 gScan(8, SROWS / 64);
    for (int u = 0; u < 23; u++) {
        float* Sp = (u & 1) ? Sb1 : Sb0;
        float* Mn = (u & 1) ? Sb0 : Sb1;
        scan_k1<<<gScan, 256, 0, stream>>>(Sp, RM, Wz_bot, Wh_bot, Xz, Xh, Mn, hs, u);
        scan_k2<<<gScan, 256, 0, stream>>>(Mn, Ur_w, Xr, RM, u);
    }
    hv_fixup<<<(22 * STEPF + 255) / 256, 256, 0, stream>>>(hs);

    // p path FIRST (frees X blocks for ql alias)
    p_init<<<(PROWS + 255) / 256, 256, 0, stream>>>(pl, Us_b);
    p_root<<<1024, 256, 0, stream>>>(XUa, Ptv, Us_w, pl);
    dim3 gP(8, PSCAN / 64);
    p_gemm<<<gP, 256, 0, stream>>>(hs, Ub, XUa, Ptv, Us_w, pl);
    p_final<<<PROWS / 256, 256, 0, stream>>>(pl, out);

    // q path
    q_root<<<(STEPF + 255) / 256, 256, 0, stream>>>(Qtv, qh);
    dim3 gQh(8, (NF * 1024) / 64);
    gemm_t<bf16, bf16><<<gQh, 256, 0, stream>>>(hs, NF * 1024, H, Wtop, H, H, qh + STEPF, H,
                                                (const float*)nullptr, Qtv, 1024, 1, H);
    dim3 gQl((V + 63) / 64, QROWS / 64);
    gemm_t<bf16, float><<<gQl, 256, 0, stream>>>(qh, QROWS, H, Wo_w, V, V, ql, V, Wo_b, (const float*)nullptr, 1, 0, H);
    q_reduce<<<QROWS, 256, 0, stream>>>(ql, wid, out);

    (void)in_sizes; (void)n_in; (void)out_size; (void)ws_size;
}

// Round 4
// 1795.550 us; speedup vs baseline: 3.7710x; 3.7710x over previous
//
#include <hip/hip_runtime.h>
#include <hip/hip_bf16.h>
#include <math.h>

#define H 450
#define HP 464            // padded A row stride (bf16 elems; 464*2B = 16B-aligned rows)
#define KP 480            // padded K extent: 15 MFMA chunks of 32
#define LAT 56
#define V 780
#define LW 24
#define NE 46
#define NF 23
#define SLOT (1024*HP)    // hs slot stride (elems)
#define SROWS 2048
#define QROWS (24*1024)
#define PROWS (47*1024)
#define PTGT  (23*1024)

typedef __hip_bfloat16 bf16;
typedef __attribute__((ext_vector_type(8))) short short8;
typedef __attribute__((ext_vector_type(4))) float f32x4;

#define MFMA16(a,b,c) __builtin_amdgcn_mfma_f32_16x16x32_bf16(a,b,c,0,0,0)

__device__ __forceinline__ float sigm(float x) { return 1.f / (1.f + expf(-x)); }
__device__ __forceinline__ float toF(bf16 x) { return __bfloat162float(x); }
__device__ __forceinline__ void stV(float* p, float v) { *p = v; }
__device__ __forceinline__ void stV(bf16* p, float v) { *p = __float2bfloat16(v); }
__device__ __forceinline__ short8 ld8(const bf16* p) { return *reinterpret_cast<const short8*>(p); }

// ---------------------------------------------------------------------------
// weight transpose+cast: dst[n*KP+k] = (n<N && k<K) ? src[k*ld+n] : 0
__global__ __launch_bounds__(256)
void make_bt(const float* __restrict__ src, int K, int N, int ld,
             bf16* __restrict__ dst, int npad) {
    int idx = blockIdx.x * 256 + threadIdx.x;
    if (idx >= npad * KP) return;
    int n = idx / KP, k = idx - n * KP;
    float v = (n < N && k < K) ? src[(size_t)k * ld + n] : 0.f;
    dst[idx] = __float2bfloat16(v);
}

__global__ __launch_bounds__(256)
void zero_init(float* __restrict__ out, float* __restrict__ Sb, int n) {
    int i = blockIdx.x * 256 + threadIdx.x;
    if (i < 4) out[i] = 0.f;
    if (i < n) Sb[i] = 0.f;
}

// x_all[t*1024+n][h] = emb[wid[n][t]][h]  (bf16, stride HP)
__global__ __launch_bounds__(256)
void gather_x(const float* __restrict__ emb, const int* __restrict__ wid,
              bf16* __restrict__ x_all) {
    int e = blockIdx.x * 256 + threadIdx.x;
    if (e >= 24 * 1024 * 225) return;
    int row = e / 225, h2 = e - row * 225;
    int t = row >> 10, n = row & 1023;
    int v = wid[n * LW + t];
    float2 x = ((const float2*)(emb + (size_t)v * H))[h2];
    bf16* dst = x_all + (size_t)row * HP + 2 * h2;
    dst[0] = __float2bfloat16(x.x);
    dst[1] = __float2bfloat16(x.y);
}

// ---------------------------------------------------------------------------
// Generic MFMA GEMM: C[Mx N] = act(A @ B + bias + addrow[(r&1023)*addld+c])
// A bf16 (lda), Bt bf16 (Npad x KP), 64x64 block tile, 4 waves 2x2, 2x2 frags.
// ---------------------------------------------------------------------------
template<typename TC>
__global__ __launch_bounds__(256)
void gemm_mfma(const bf16* __restrict__ A, int lda,
               const bf16* __restrict__ Bt, int N,
               TC* __restrict__ C, int ldc,
               const float* __restrict__ bias,
               const float* __restrict__ addrow, int addld, int relu) {
    int tid = threadIdx.x;
    int lane = tid & 63, wave = tid >> 6;
    int wx = wave & 1, wy = wave >> 1;
    int lrow = lane & 15, quad = lane >> 4;
    int row0 = blockIdx.y * 64, col0 = blockIdx.x * 64;
    const bf16* a0 = A + (size_t)(row0 + wy * 32 + lrow) * lda + quad * 8;
    const bf16* a1 = a0 + (size_t)16 * lda;
    const bf16* b0 = Bt + (size_t)(col0 + wx * 32 + lrow) * KP + quad * 8;
    const bf16* b1 = b0 + 16 * KP;
    f32x4 acc[2][2] = {};
    for (int k = 0; k < 15; k++) {
        short8 af0 = ld8(a0 + k * 32);
        short8 af1 = ld8(a1 + k * 32);
        short8 bf0 = ld8(b0 + k * 32);
        short8 bf1 = ld8(b1 + k * 32);
        acc[0][0] = MFMA16(af0, bf0, acc[0][0]);
        acc[0][1] = MFMA16(af0, bf1, acc[0][1]);
        acc[1][0] = MFMA16(af1, bf0, acc[1][0]);
        acc[1][1] = MFMA16(af1, bf1, acc[1][1]);
    }
#pragma unroll
    for (int i = 0; i < 2; i++)
#pragma unroll
        for (int e = 0; e < 4; e++) {
            int r = row0 + wy * 32 + i * 16 + quad * 4 + e;
#pragma unroll
            for (int j = 0; j < 2; j++) {
                int c = col0 + wx * 32 + j * 16 + lrow;
                if (c >= N) continue;
                float v = acc[i][j][e];
                if (bias) v += bias[c];
                if (addrow) v += addrow[(size_t)(r & 1023) * addld + c];
                if (relu) v = fmaxf(v, 0.f);
                stV(&C[(size_t)r * ldc + c], v);
            }
        }
}

// Qtv/Ptv: out[n][c] = tv[n](56) @ Wlat(56x450) + bias[c]   grid(2,1024), fp32
__global__ __launch_bounds__(256)
void tv_gemm(const float* __restrict__ tv, const float* __restrict__ Wlat,
             const float* __restrict__ bias, float* __restrict__ out) {
    int n = blockIdx.y;
    int c = blockIdx.x * 256 + threadIdx.x;
    __shared__ float tvs[LAT];
    if (threadIdx.x < LAT) tvs[threadIdx.x] = tv[n * LAT + threadIdx.x];
    __syncthreads();
    if (c < H) {
        float a = bias[c];
#pragma unroll 8
        for (int k = 0; k < LAT; k++) a += tvs[k] * Wlat[(size_t)k * H + c];
        out[(size_t)n * H + c] = a;
    }
}

// ---------------------------------------------------------------------------
// Scan K1 (MFMA): z_pre = S@Wzb, h_pre = RM@Whb  (M=2048,N=450,K=450)
// A(S): hs slot u-1 (fwd rows) / 23+u-1 (bwd); A(RM): RMb. skip => acc=0 (u=0).
// epilogue: z=sig(zp+Xz[src]); mt=tanh(hp+Xh[src]); mn=(1-z)s+z*mt
//           Sb in-place fp32; hs slot (u / 23+u) gets bf16(mn).
// ---------------------------------------------------------------------------
__global__ __launch_bounds__(256)
void scan_k1(const bf16* __restrict__ AsF, const bf16* __restrict__ AsB,
             const bf16* __restrict__ Arm,
             const bf16* __restrict__ BzT, const bf16* __restrict__ BhT,
             const bf16* __restrict__ Xz, const bf16* __restrict__ Xh,
             float* __restrict__ Sb, bf16* __restrict__ hsF, bf16* __restrict__ hsB,
             int u, int skip) {
    int tid = threadIdx.x;
    int lane = tid & 63, wave = tid >> 6;
    int wx = wave & 1, wy = wave >> 1;
    int lrow = lane & 15, quad = lane >> 4;
    int row0 = blockIdx.y * 64, col0 = blockIdx.x * 64;
    bool fwd = row0 < 1024;
    int rb = row0 & 1023;
    f32x4 az[2][2] = {}, ah[2][2] = {};
    if (!skip) {
        const bf16* As = (fwd ? AsF : AsB) + (size_t)(rb + wy * 32 + lrow) * HP + quad * 8;
        const bf16* Ar = Arm + (size_t)(row0 + wy * 32 + lrow) * HP + quad * 8;
        const bf16* bz0 = BzT + (size_t)(col0 + wx * 32 + lrow) * KP + quad * 8;
        const bf16* bh0 = BhT + (size_t)(col0 + wx * 32 + lrow) * KP + quad * 8;
        for (int k = 0; k < 15; k++) {
            short8 s0 = ld8(As + k * 32);
            short8 s1 = ld8(As + (size_t)16 * HP + k * 32);
            short8 r0 = ld8(Ar + k * 32);
            short8 r1 = ld8(Ar + (size_t)16 * HP + k * 32);
            short8 z0 = ld8(bz0 + k * 32);
            short8 z1 = ld8(bz0 + 16 * KP + k * 32);
            short8 h0 = ld8(bh0 + k * 32);
            short8 h1 = ld8(bh0 + 16 * KP + k * 32);
            az[0][0] = MFMA16(s0, z0, az[0][0]);
            az[0][1] = MFMA16(s0, z1, az[0][1]);
            az[1][0] = MFMA16(s1, z0, az[1][0]);
            az[1][1] = MFMA16(s1, z1, az[1][1]);
            ah[0][0] = MFMA16(r0, h0, ah[0][0]);
            ah[0][1] = MFMA16(r0, h1, ah[0][1]);
            ah[1][0] = MFMA16(r1, h0, ah[1][0]);
            ah[1][1] = MFMA16(r1, h1, ah[1][1]);
        }
    }
    int src = fwd ? u : 23 - u;
    bf16* hso = fwd ? hsF : hsB;
#pragma unroll
    for (int i = 0; i < 2; i++)
#pragma unroll
        for (int e = 0; e < 4; e++) {
            int r = row0 + wy * 32 + i * 16 + quad * 4 + e;
            int n = r & 1023;
#pragma unroll
            for (int j = 0; j < 2; j++) {
                int c = col0 + wx * 32 + j * 16 + lrow;
                if (c >= H) continue;
                float zp = az[i][j][e] + toF(Xz[((size_t)src * 1024 + n) * H + c]);
                float hp = ah[i][j][e] + toF(Xh[((size_t)src * 1024 + n) * H + c]);
                float s  = Sb[(size_t)r * H + c];
                float z  = sigm(zp);
                float mt = tanhf(hp);
                float mn = (1.f - z) * s + z * mt;
                Sb[(size_t)r * H + c] = mn;
                hso[(size_t)n * HP + c] = __float2bfloat16(mn);
            }
        }
}

// Scan K2 (MFMA): r_pre = Mnew@Ur + Xr[dst]; RMb = bf16(sig(r_pre)*Mnew)
__global__ __launch_bounds__(256)
void scan_k2(const bf16* __restrict__ AmF, const bf16* __restrict__ AmB,
             const bf16* __restrict__ UrT, const bf16* __restrict__ Xr,
             const float* __restrict__ Sb, bf16* __restrict__ RMb, int u) {
    int tid = threadIdx.x;
    int lane = tid & 63, wave = tid >> 6;
    int wx = wave & 1, wy = wave >> 1;
    int lrow = lane & 15, quad = lane >> 4;
    int row0 = blockIdx.y * 64, col0 = blockIdx.x * 64;
    bool fwd = row0 < 1024;
    int rb = row0 & 1023;
    const bf16* Am = (fwd ? AmF : AmB) + (size_t)(rb + wy * 32 + lrow) * HP + quad * 8;
    const bf16* b0 = UrT + (size_t)(col0 + wx * 32 + lrow) * KP + quad * 8;
    f32x4 acc[2][2] = {};
    for (int k = 0; k < 15; k++) {
        short8 a0 = ld8(Am + k * 32);
        short8 a1 = ld8(Am + (size_t)16 * HP + k * 32);
        short8 w0 = ld8(b0 + k * 32);
        short8 w1 = ld8(b0 + 16 * KP + k * 32);
        acc[0][0] = MFMA16(a0, w0, acc[0][0]);
        acc[0][1] = MFMA16(a0, w1, acc[0][1]);
        acc[1][0] = MFMA16(a1, w0, acc[1][0]);
        acc[1][1] = MFMA16(a1, w1, acc[1][1]);
    }
    int dst = fwd ? (u + 1) : (22 - u);
#pragma unroll
    for (int i = 0; i < 2; i++)
#pragma unroll
        for (int e = 0; e < 4; e++) {
            int r = row0 + wy * 32 + i * 16 + quad * 4 + e;
            int n = r & 1023;
#pragma unroll
            for (int j = 0; j < 2; j++) {
                int c = col0 + wx * 32 + j * 16 + lrow;
                if (c >= H) continue;
                float rp = acc[i][j][e] + toF(Xr[((size_t)dst * 1024 + n) * H + c]);
                float rr = sigm(rp);
                RMb[(size_t)r * HP + c] = __float2bfloat16(rr * Sb[(size_t)r * H + c]);
            }
        }
}

// hs[t] += hs[44-t] for t in 23..44 (bwd h_v gets fwd m[i-1]); full HP rows
__global__ __launch_bounds__(256)
void hv_fixup(bf16* __restrict__ hs) {
    int idx = blockIdx.x * 256 + threadIdx.x;
    if (idx >= 22 * SLOT) return;
    int tl = idx / SLOT;
    int rem = idx - tl * SLOT;
    int t = 23 + tl;
    float v = toF(hs[(size_t)t * SLOT + rem]) + toF(hs[(size_t)(44 - t) * SLOT + rem]);
    hs[(size_t)t * SLOT + rem] = __float2bfloat16(v);
}

// q_hidden root rows: relu(Qtv) -> qh rows 0..1023 (stride HP)
__global__ __launch_bounds__(256)
void q_root(const float* __restrict__ Qtv, bf16* __restrict__ qh) {
    int idx = blockIdx.x * 256 + threadIdx.x;
    if (idx >= 1024 * H) return;
    int n = idx / H, c = idx - n * H;
    qh[(size_t)n * HP + c] = __float2bfloat16(fmaxf(Qtv[idx], 0.f));
}

// Per-row log-softmax CE + argmax accuracy over V=780. One block per row.
__global__ __launch_bounds__(256)
void q_reduce(const float* __restrict__ ql, const int* __restrict__ wid,
              float* __restrict__ out) {
    __shared__ float sv[256];
    __shared__ int   si[256];
    __shared__ float ss[256];
    int r = blockIdx.x;
    int t = r >> 10, n = r & 1023;
    int tgt = wid[n * LW + t];
    const float* row = ql + (size_t)r * V;
    int tid = threadIdx.x;
    float mx = -3.4e38f; int mi = V;
    for (int c = tid; c < V; c += 256) {
        float v = row[c];
        if (v > mx) { mx = v; mi = c; }
    }
    sv[tid] = mx; si[tid] = mi;
    __syncthreads();
    for (int s = 128; s > 0; s >>= 1) {
        if (tid < s) {
            float v2 = sv[tid + s]; int i2 = si[tid + s];
            if (v2 > sv[tid] || (v2 == sv[tid] && i2 < si[tid])) { sv[tid] = v2; si[tid] = i2; }
        }
        __syncthreads();
    }
    float MX = sv[0]; int AI = si[0];
    float se = 0.f;
    for (int c = tid; c < V; c += 256) se += expf(row[c] - MX);
    ss[tid] = se;
    __syncthreads();
    for (int s = 128; s > 0; s >>= 1) {
        if (tid < s) ss[tid] += ss[tid + s];
        __syncthreads();
    }
    if (tid == 0) {
        float lse = MX + logf(ss[0]);
        atomicAdd(&out[0], (lse - row[tgt]) * (1.f / 1024.f));
        if (AI == tgt) atomicAdd(&out[2], 1.f / 24576.f);
    }
}

__global__ __launch_bounds__(256)
void p_init(float* __restrict__ pl, const float* __restrict__ Us_b) {
    int idx = blockIdx.x * 256 + threadIdx.x;
    if (idx < PROWS) pl[idx] = Us_b[0];
}

__global__ __launch_bounds__(256)
void p_root(const bf16* __restrict__ XUa, const float* __restrict__ Ptv,
            const float* __restrict__ Us, float* __restrict__ pl) {
    int n = blockIdx.x;
    int tid = threadIdx.x;
    const bf16* xa = XUa + (size_t)n * H;
    const float* pt = Ptv + (size_t)n * H;
    float s = 0.f;
    for (int c = tid; c < H; c += 256)
        s += fmaxf(toF(xa[c]) + pt[c], 0.f) * Us[c];
    __shared__ float red[256];
    red[tid] = s;
    __syncthreads();
    for (int k = 128; k > 0; k >>= 1) {
        if (tid < k) red[tid] += red[tid + k];
        __syncthreads();
    }
    if (tid == 0) atomicAdd(&pl[n], red[0]);
}

// p scan rows (MFMA): hs(47104xH)@Ub; epilogue relu(+XUa[dst]+Ptv) dot Us -> pl
__global__ __launch_bounds__(256)
void p_gemm(const bf16* __restrict__ hs, const bf16* __restrict__ UbT,
            const bf16* __restrict__ XUa, const float* __restrict__ Ptv,
            const float* __restrict__ Us, float* __restrict__ pl) {
    int tid = threadIdx.x;
    int lane = tid & 63, wave = tid >> 6;
    int wx = wave & 1, wy = wave >> 1;
    int lrow = lane & 15, quad = lane >> 4;
    int row0 = blockIdx.y * 64, col0 = blockIdx.x * 64;
    const bf16* a0 = hs + (size_t)(row0 + wy * 32 + lrow) * HP + quad * 8;
    const bf16* b0 = UbT + (size_t)(col0 + wx * 32 + lrow) * KP + quad * 8;
    f32x4 acc[2][2] = {};
    for (int k = 0; k < 15; k++) {
        short8 af0 = ld8(a0 + k * 32);
        short8 af1 = ld8(a0 + (size_t)16 * HP + k * 32);
        short8 bf0 = ld8(b0 + k * 32);
        short8 bf1 = ld8(b0 + 16 * KP + k * 32);
        acc[0][0] = MFMA16(af0, bf0, acc[0][0]);
        acc[0][1] = MFMA16(af0, bf1, acc[0][1]);
        acc[1][0] = MFMA16(af1, bf0, acc[1][0]);
        acc[1][1] = MFMA16(af1, bf1, acc[1][1]);
    }
    __shared__ float red[64][32];
#pragma unroll
    for (int i = 0; i < 2; i++)
#pragma unroll
        for (int e = 0; e < 4; e++) {
            int rl = wy * 32 + i * 16 + quad * 4 + e;
            int r = row0 + rl;
            int t = r >> 10, n = r & 1023;
            int dst = (t < 23) ? (t + 1) : (45 - t);
            float partial = 0.f;
#pragma unroll
            for (int j = 0; j < 2; j++) {
                int c = col0 + wx * 32 + j * 16 + lrow;
                if (c < H) {
                    float h = fmaxf(acc[i][j][e] + toF(XUa[((size_t)dst * 1024 + n) * H + c])
                                    + Ptv[(size_t)n * H + c], 0.f);
                    partial += h * Us[c];
                }
            }
            red[rl][wx * 16 + lrow] = partial;
        }
    __syncthreads();
    if (tid < 64) {
        float s = 0.f;
#pragma unroll
        for (int k = 0; k < 32; k++) s += red[tid][k];
        atomicAdd(&pl[1024 + row0 + tid], s);
    }
}

// BCE loss + accuracy over 48128 rows; target = (r < 23552)
__global__ __launch_bounds__(256)
void p_final(const float* __restrict__ pl, float* __restrict__ out) {
    int r = blockIdx.x * 256 + threadIdx.x;
    int tid = threadIdx.x;
    float loss = 0.f, acc = 0.f;
    if (r < PROWS) {
        float l = pl[r];
        int tgt = (r < PTGT) ? 1 : 0;
        float x = tgt ? -l : l;
        loss = fmaxf(x, 0.f) + log1pf(expf(-fabsf(x)));
        int pred = (l > 0.f) ? 1 : 0;
        acc = (pred == tgt) ? 1.f : 0.f;
    }
    __shared__ float s1[256], s2[256];
    s1[tid] = loss; s2[tid] = acc;
    __syncthreads();
    for (int k = 128; k > 0; k >>= 1) {
        if (tid < k) { s1[tid] += s1[tid + k]; s2[tid] += s2[tid + k]; }
        __syncthreads();
    }
    if (tid == 0) {
        atomicAdd(&out[1], s1[0] * (1.f / 1024.f));
        atomicAdd(&out[3], s2[0] * (1.f / 48128.f));
    }
}

// ---------------------------------------------------------------------------
extern "C" void kernel_launch(void* const* d_in, const int* in_sizes, int n_in,
                              void* d_out, int out_size, void* d_ws, size_t ws_size,
                              hipStream_t stream) {
    const int*   wid  = (const int*)  d_in[0];
    const float* tv   = (const float*)d_in[1];
    const float* emb  = (const float*)d_in[2];
    const float* W_w  = (const float*)d_in[3];
    const float* W_b  = (const float*)d_in[4];
    const float* U_w  = (const float*)d_in[5];
    const float* U_b  = (const float*)d_in[6];
    const float* Wo_w = (const float*)d_in[7];
    const float* Wo_b = (const float*)d_in[8];
    const float* Us_w = (const float*)d_in[9];
    const float* Us_b = (const float*)d_in[10];
    const float* Wz_w = (const float*)d_in[11];
    const float* Wz_b = (const float*)d_in[12];
    const float* Wr_w = (const float*)d_in[13];
    const float* Ur_w = (const float*)d_in[14];
    const float* Ur_b = (const float*)d_in[15];
    const float* Wh_w = (const float*)d_in[16];
    const float* Wh_b = (const float*)d_in[17];
    float* out = (float*)d_out;

    // ---- workspace layout (bytes), total ~140 MiB ----
    char* base = (char*)d_ws;
    const size_t XBb   = (size_t)QROWS * H * 2;          // 22,118,400 B per X block
    bf16*  Xz   = (bf16*)(base);
    bf16*  Xh   = (bf16*)(base + XBb);
    bf16*  Xr   = (bf16*)(base + 2 * XBb);
    bf16*  XUa  = (bf16*)(base + 3 * XBb);
    bf16*  hs   = (bf16*)(base + 4 * XBb);               // 46 slots x 1024 x HP bf16
    bf16*  x_all = hs;                                   // alias (dead before scan)
    char*  p1   = base + 4 * XBb + (size_t)NE * SLOT * 2;
    bf16*  RMb  = (bf16*)p1;                p1 += (size_t)SROWS * HP * 2;
    float* Sb   = (float*)p1;               p1 += (size_t)SROWS * H * 4;
    float* Qtv  = (float*)p1;               p1 += (size_t)1024 * H * 4;
    float* Ptv  = (float*)p1;               p1 += (size_t)1024 * H * 4;
    float* pl   = (float*)p1;               p1 += (size_t)PROWS * 4;
    bf16*  BT   = (bf16*)p1;                             // 9 x 512*KP + 832*KP
    const size_t BTS = (size_t)512 * KP;
    bf16 *WztT = BT,           *WhtT = BT + BTS,     *WrT = BT + 2*BTS,
         *UaT  = BT + 3*BTS,   *WzbT = BT + 4*BTS,   *WhbT = BT + 5*BTS,
         *UrT  = BT + 6*BTS,   *UbT  = BT + 7*BTS,   *WtopT = BT + 8*BTS,
         *WoT  = BT + 9*BTS;                             // 832*KP
    // q-path aliases (used after p path completes):
    bf16*  qh = (bf16*)base;                             // 24576 x HP bf16 (~22.8 MB)
    float* ql = (float*)(base + (size_t)QROWS * HP * 2); // 24576 x 780 f32 (~76.7 MB)

    // ---- init + weight prep ----
    zero_init<<<(SROWS * H + 255) / 256, 256, 0, stream>>>(out, Sb, SROWS * H);
    int btg = (512 * KP + 255) / 256;
    make_bt<<<btg, 256, 0, stream>>>(Wz_w,            H, H, H, WztT, 512);
    make_bt<<<btg, 256, 0, stream>>>(Wh_w,            H, H, H, WhtT, 512);
    make_bt<<<btg, 256, 0, stream>>>(Wr_w,            H, H, H, WrT,  512);
    make_bt<<<btg, 256, 0, stream>>>(U_w,             H, H, H, UaT,  512);
    make_bt<<<btg, 256, 0, stream>>>(Wz_w + 450*450,  H, H, H, WzbT, 512);
    make_bt<<<btg, 256, 0, stream>>>(Wh_w + 450*450,  H, H, H, WhbT, 512);
    make_bt<<<btg, 256, 0, stream>>>(Ur_w,            H, H, H, UrT,  512);
    make_bt<<<btg, 256, 0, stream>>>(U_w + 450*450,   H, H, H, UbT,  512);
    make_bt<<<btg, 256, 0, stream>>>(W_w,             H, H, H, WtopT, 512);
    make_bt<<<(832 * KP + 255) / 256, 256, 0, stream>>>(Wo_w, H, V, V, WoT, 832);

    // ---- embedding gather + per-node precomputes ----
    gather_x<<<(24 * 1024 * 225 + 255) / 256, 256, 0, stream>>>(emb, wid, x_all);
    dim3 gPre(8, QROWS / 64);
    gemm_mfma<bf16><<<gPre, 256, 0, stream>>>(x_all, HP, WztT, H, Xz,  H, Wz_b, (const float*)nullptr, H, 0);
    gemm_mfma<bf16><<<gPre, 256, 0, stream>>>(x_all, HP, WhtT, H, Xh,  H, Wh_b, (const float*)nullptr, H, 0);
    gemm_mfma<bf16><<<gPre, 256, 0, stream>>>(x_all, HP, WrT,  H, Xr,  H, Ur_b, (const float*)nullptr, H, 0);
    gemm_mfma<bf16><<<gPre, 256, 0, stream>>>(x_all, HP, UaT,  H, XUa, H, (const float*)nullptr, (const float*)nullptr, H, 0);

    tv_gemm<<<dim3(2, 1024), 256, 0, stream>>>(tv, W_w + 450*450, W_b, Qtv);
    tv_gemm<<<dim3(2, 1024), 256, 0, stream>>>(tv, U_w + 900*450, U_b, Ptv);

    // ---- sequential scan: 23 steps, fwd+bwd chains batched (M=2048) ----
    dim3 gScan(8, SROWS / 64);
    for (int u = 0; u < 23; u++) {
        const bf16* AsF = hs + (size_t)(u - 1) * SLOT;        // valid only u>0
        const bf16* AsB = hs + (size_t)(22 + u) * SLOT;
        scan_k1<<<gScan, 256, 0, stream>>>(AsF, AsB, RMb, WzbT, WhbT, Xz, Xh,
                                           Sb, hs + (size_t)u * SLOT,
                                           hs + (size_t)(23 + u) * SLOT, u, u == 0 ? 1 : 0);
        scan_k2<<<gScan, 256, 0, stream>>>(hs + (size_t)u * SLOT, hs + (size_t)(23 + u) * SLOT,
                                           UrT, Xr, Sb, RMb, u);
    }
    hv_fixup<<<(22 * SLOT + 255) / 256, 256, 0, stream>>>(hs);

    // ---- p path (before q aliases X blocks / hs) ----
    p_init<<<(PROWS + 255) / 256, 256, 0, stream>>>(pl, Us_b);
    p_root<<<1024, 256, 0, stream>>>(XUa, Ptv, Us_w, pl);
    dim3 gP(8, (NE * 1024) / 64);
    p_gemm<<<gP, 256, 0, stream>>>(hs, UbT, XUa, Ptv, Us_w, pl);
    p_final<<<PROWS / 256, 256, 0, stream>>>(pl, out);

    // ---- q path (qh over Xz/Xh; ql over Xr/XUa/hs-head) ----
    q_root<<<(1024 * H + 255) / 256, 256, 0, stream>>>(Qtv, qh);
    dim3 gQh(8, (NF * 1024) / 64);
    gemm_mfma<bf16><<<gQh, 256, 0, stream>>>(hs, HP, WtopT, H, qh + (size_t)1024 * HP, HP,
                                             (const float*)nullptr, Qtv, H, 1);
    dim3 gQl(13, QROWS / 64);
    gemm_mfma<float><<<gQl, 256, 0, stream>>>(qh, HP, WoT, V, ql, V, Wo_b, (const float*)nullptr, H, 0);
    q_reduce<<<QROWS, 256, 0, stream>>>(ql, wid, out);

    (void)in_sizes; (void)n_in; (void)out_size; (void)ws_size;
}